// Round 3
// baseline (192.141 us; speedup 1.0000x reference)
//
#include <hip/hip_runtime.h>
#include <math.h>

namespace {
constexpr int Bn = 2, CF = 64, CHN = 32;
constexpr int H = 256, W = 256, HW = H * W;
constexpr int IH = 512, IW = 512;

// ws layout in floats
constexpr int OFF_M   = 0;                   // 256*256 = 65536
constexpr int OFF_GXX = OFF_M + 256 * 256;   // 256*3
constexpr int OFF_GYY = OFF_GXX + 256 * 3;   // 256*3
constexpr int OFF_EM  = OFF_GYY + 256 * 3;   // = 67072 (byte off 268288, 16B aligned)
constexpr int OFF_S   = OFF_EM + Bn * CHN * HW;  // Bn*HW
constexpr int OFF_PHI = OFF_S + Bn * HW;         // Bn*9*HW = 1179648
// total floats = 67072 + 4194304 + 131072 + 1179648 = 5572096 (~22.3 MB)
// PX/PY (32*256 each) OVERLAY the em region: consumed by gram_kernel before
// em_s_kernel overwrites it (same stream => ordered).
constexpr int OFF_PX  = OFF_EM;
constexpr int OFF_PY  = OFF_EM + 32 * 256;
}

// ---------------------------------------------------------------------------
// P1: PX[o][t] = sum_i wpos[o][2i]*sin(t*div_i) + wpos[o][2i+1]*cos(t*div_i)
//     PY[o][t] = same with wpos[o][32+...]
// ---------------------------------------------------------------------------
__global__ __launch_bounds__(256) void pxy_kernel(
    const float* __restrict__ w_pos,
    float* __restrict__ PX, float* __restrict__ PY)
{
  const int t = threadIdx.x;
  const int o = blockIdx.x;
  float s[16], c[16];
#pragma unroll
  for (int i = 0; i < 16; i++) {
    float d = expf((float)(2 * i) * (-0.2878231366242557f)); // -ln(1e4)/32
    float a = (float)t * d;
    s[i] = sinf(a);
    c[i] = cosf(a);
  }
  const float* wr = w_pos + o * 64;
  float ax = 0.f, ay = 0.f;
#pragma unroll
  for (int i = 0; i < 16; i++) {
    ax += wr[2 * i] * s[i] + wr[2 * i + 1] * c[i];
    ay += wr[32 + 2 * i] * s[i] + wr[33 + 2 * i] * c[i];
  }
  PX[o * 256 + t] = ax;
  PY[o * 256 + t] = ay;
}

// ---------------------------------------------------------------------------
// P2: M[a][t] = dot_o(PX[:,a], PY[:,t]);
//     GXX[a][j] = dot_o(PX[:,a], PX[:,a+2(j-1)]) (0 if OOB; masked downstream)
//     GYY[a][j] likewise on PY.
// ---------------------------------------------------------------------------
__global__ __launch_bounds__(256) void gram_kernel(
    const float* __restrict__ PX, const float* __restrict__ PY,
    float* __restrict__ M, float* __restrict__ GXX, float* __restrict__ GYY)
{
  const int t = threadIdx.x;
  const int a = blockIdx.x;

  __shared__ float pxa[32], pxm[32], pxp[32], pya[32], pym[32], pyp[32];
  if (t < 32) {
    pxa[t] = PX[t * 256 + a];
    pya[t] = PY[t * 256 + a];
    pxm[t] = (a >= 2)  ? PX[t * 256 + a - 2] : 0.f;
    pxp[t] = (a < 254) ? PX[t * 256 + a + 2] : 0.f;
    pym[t] = (a >= 2)  ? PY[t * 256 + a - 2] : 0.f;
    pyp[t] = (a < 254) ? PY[t * 256 + a + 2] : 0.f;
  }
  __syncthreads();

  float m = 0.f;
#pragma unroll
  for (int o = 0; o < 32; o++) m += pxa[o] * PY[o * 256 + t];
  M[a * 256 + t] = m;

  if (t < 3) {
    const float* sel = (t == 0) ? pxm : (t == 1) ? pxa : pxp;
    float g = 0.f;
#pragma unroll
    for (int o = 0; o < 32; o++) g += pxa[o] * sel[o];
    GXX[a * 3 + t] = g;
  } else if (t < 6) {
    const int j = t - 3;
    const float* sel = (j == 0) ? pym : (j == 1) ? pya : pyp;
    float g = 0.f;
#pragma unroll
    for (int o = 0; o < 32; o++) g += pya[o] * sel[o];
    GYY[a * 3 + j] = g;
  }
}

// ---------------------------------------------------------------------------
// Kernel 1: em_img (channel-last [b][pix][32]) + smap.
// ---------------------------------------------------------------------------
__device__ __forceinline__ void resize_taps(int p, int n, float w[4], int idx[4])
{
#pragma unroll
  for (int r = 0; r < 4; r++) {
    int q = 2 * p - 1 + r;
    idx[r] = min(max(q, 0), 2 * n - 1);
  }
  if (p == 0)          { w[0] = 0.f;        w[1] = 3.f / 7.f; w[2] = 3.f / 7.f; w[3] = 1.f / 7.f; }
  else if (p == n - 1) { w[0] = 1.f / 7.f;  w[1] = 3.f / 7.f; w[2] = 3.f / 7.f; w[3] = 0.f; }
  else                 { w[0] = 0.125f;     w[1] = 0.375f;    w[2] = 0.375f;    w[3] = 0.125f; }
}

__global__ __launch_bounds__(256) void em_s_kernel(
    const float* __restrict__ inp, const float* __restrict__ img,
    const float* __restrict__ w_img, const float* __restrict__ w_comp,
    float* __restrict__ em, float* __restrict__ smap)
{
  const int x = blockIdx.x * 64 + threadIdx.x;
  const int y = blockIdx.y * 4 + threadIdx.y;
  const int b = blockIdx.z;
  const int pix = y * W + x;

  float wy[4], wx[4];
  int ry[4], rx[4];
  resize_taps(y, H, wy, ry);
  resize_taps(x, W, wx, rx);

  float rimg[3];
#pragma unroll
  for (int c = 0; c < 3; c++) {
    const float* ip = img + ((b * 3 + c) * IH) * IW;
    float acc = 0.f;
#pragma unroll
    for (int r = 0; r < 4; r++) {
      const float* rowp = ip + ry[r] * IW;
      float rs = wx[0] * rowp[rx[0]] + wx[1] * rowp[rx[1]] +
                 wx[2] * rowp[rx[2]] + wx[3] * rowp[rx[3]];
      acc += wy[r] * rs;
    }
    rimg[c] = acc;
  }

  float* ep = em + ((size_t)b * HW + pix) * CHN;
#pragma unroll
  for (int o8 = 0; o8 < 8; o8++) {
    float4 v;
    v.x = w_img[(4 * o8 + 0) * 3] * rimg[0] + w_img[(4 * o8 + 0) * 3 + 1] * rimg[1] + w_img[(4 * o8 + 0) * 3 + 2] * rimg[2];
    v.y = w_img[(4 * o8 + 1) * 3] * rimg[0] + w_img[(4 * o8 + 1) * 3 + 1] * rimg[1] + w_img[(4 * o8 + 1) * 3 + 2] * rimg[2];
    v.z = w_img[(4 * o8 + 2) * 3] * rimg[0] + w_img[(4 * o8 + 2) * 3 + 1] * rimg[1] + w_img[(4 * o8 + 2) * 3 + 2] * rimg[2];
    v.w = w_img[(4 * o8 + 3) * 3] * rimg[0] + w_img[(4 * o8 + 3) * 3 + 1] * rimg[1] + w_img[(4 * o8 + 3) * 3 + 2] * rimg[2];
    ((float4*)ep)[o8] = v;
  }

  const float* inpb = inp + (size_t)b * CF * HW;
  float s = 0.f;
#pragma unroll
  for (int c = 0; c < CF; c++) s += inpb[c * HW + pix] * w_comp[c];
  smap[b * HW + pix] = s;
}

// ---------------------------------------------------------------------------
// Kernel A: phi[b][k][pix] = valid_k * sigmoid(smap[nb]) *
//   ( dot32(em[nb], em[ctr]) + GXX[x,kx] + GYY[y,ky] + M[nx,y] + M[x,ny] )
// One thread per (b,k,pixel): 1.18M threads -> latency fully hidden by TLP.
// Grid x = pixel blocks (fast axis) so each XCD re-reads the same em slice
// from its L2 across the 9 k-sweeps.
// ---------------------------------------------------------------------------
__global__ __launch_bounds__(256) void phi_kernel(
    const float* __restrict__ em, const float* __restrict__ smap,
    const float* __restrict__ M, const float* __restrict__ GXX,
    const float* __restrict__ GYY, float* __restrict__ phi)
{
  const int p = blockIdx.x * 256 + threadIdx.x;  // pixel
  const int k = blockIdx.y;                      // neighbor 0..8
  const int b = blockIdx.z;
  const int x = p & (W - 1);
  const int y = p >> 8;
  const int ky = k / 3, kx = k % 3;
  const int ny = y + 2 * (ky - 1), nx = x + 2 * (kx - 1);
  const bool valid = ((unsigned)ny < (unsigned)H) & ((unsigned)nx < (unsigned)W);
  const int cny = min(max(ny, 0), H - 1);
  const int cnx = min(max(nx, 0), W - 1);
  const int np = cny * W + cnx;

  const float* emb = em + (size_t)b * HW * CHN;
  const float4* ec = (const float4*)(emb + (size_t)p * CHN);
  const float4* en = (const float4*)(emb + (size_t)np * CHN);
  float fs = 0.f;
#pragma unroll
  for (int i = 0; i < 8; i++) {
    float4 a = ec[i], v = en[i];
    fs += a.x * v.x + a.y * v.y + a.z * v.z + a.w * v.w;
  }
  fs += GXX[x * 3 + kx] + GYY[y * 3 + ky] + M[cnx * 256 + y] + M[x * 256 + cny];

  const float s = smap[b * HW + np];
  const float cs = 1.f / (1.f + expf(-s));
  phi[((size_t)(b * 9 + k)) * HW + p] = valid ? cs * fs : 0.f;
}

// ---------------------------------------------------------------------------
// Kernel B: out[b,c,p] = sum_k phi[b][k][p] * inp[b,c,nb_k]
// One thread per (b, 8-channel group, pixel): 1.05M threads.
// ---------------------------------------------------------------------------
__global__ __launch_bounds__(256) void gather_kernel(
    const float* __restrict__ inp, const float* __restrict__ phi,
    float* __restrict__ out)
{
  const int p = blockIdx.x * 256 + threadIdx.x;
  const int cg = blockIdx.y;   // channel group: channels 8*cg .. 8*cg+7
  const int b = blockIdx.z;
  const int x = p & (W - 1);
  const int y = p >> 8;

  float ph[9];
  int np[9];
#pragma unroll
  for (int k = 0; k < 9; k++) {
    const int ky = k / 3, kx = k % 3;
    const int ny = y + 2 * (ky - 1), nx = x + 2 * (kx - 1);
    const int cny = min(max(ny, 0), H - 1);
    const int cnx = min(max(nx, 0), W - 1);
    np[k] = cny * W + cnx;
    ph[k] = phi[((size_t)(b * 9 + k)) * HW + p];  // already 0 when invalid
  }

  const float* inpb = inp + (size_t)b * CF * HW + (size_t)cg * 8 * HW;
  float* outb = out + (size_t)b * CF * HW + (size_t)cg * 8 * HW;
#pragma unroll
  for (int c = 0; c < 8; c++) {
    const float* ic = inpb + c * HW;
    float acc = ph[0] * ic[np[0]];
#pragma unroll
    for (int k = 1; k < 9; k++) acc += ph[k] * ic[np[k]];
    outb[c * HW + p] = acc;
  }
}

// ---------------------------------------------------------------------------
extern "C" void kernel_launch(void* const* d_in, const int* in_sizes, int n_in,
                              void* d_out, int out_size, void* d_ws, size_t ws_size,
                              hipStream_t stream)
{
  const float* inp    = (const float*)d_in[0];
  const float* img    = (const float*)d_in[1];
  const float* w_pos  = (const float*)d_in[2];
  const float* w_img  = (const float*)d_in[3];
  const float* w_comp = (const float*)d_in[4];
  float* out = (float*)d_out;
  float* ws  = (float*)d_ws;

  float* M    = ws + OFF_M;
  float* GXX  = ws + OFF_GXX;
  float* GYY  = ws + OFF_GYY;
  float* em   = ws + OFF_EM;
  float* smap = ws + OFF_S;
  float* phi  = ws + OFF_PHI;
  float* PX   = ws + OFF_PX;   // overlays em region (consumed before em written)
  float* PY   = ws + OFF_PY;

  hipLaunchKernelGGL(pxy_kernel, dim3(32), dim3(256), 0, stream, w_pos, PX, PY);
  hipLaunchKernelGGL(gram_kernel, dim3(256), dim3(256), 0, stream,
                     PX, PY, M, GXX, GYY);

  dim3 blk1(64, 4, 1), g1(W / 64, H / 4, Bn);
  hipLaunchKernelGGL(em_s_kernel, g1, blk1, 0, stream,
                     inp, img, w_img, w_comp, em, smap);

  hipLaunchKernelGGL(phi_kernel, dim3(HW / 256, 9, Bn), dim3(256), 0, stream,
                     em, smap, M, GXX, GYY, phi);

  hipLaunchKernelGGL(gather_kernel, dim3(HW / 256, CF / 8, Bn), dim3(256), 0, stream,
                     inp, phi, out);
}

// Round 4
// 178.496 us; speedup vs baseline: 1.0764x; 1.0764x over previous
//
#include <hip/hip_runtime.h>
#include <math.h>

namespace {
constexpr int Bn = 2, CF = 64, CHN = 32;
constexpr int H = 256, W = 256, HW = H * W;
constexpr int IH = 512, IW = 512;

// ws layout in floats
constexpr int OFF_M   = 0;                   // 256*256
constexpr int OFF_GXX = OFF_M + 256 * 256;   // 256*3
constexpr int OFF_GYY = OFF_GXX + 256 * 3;   // 256*3
constexpr int OFF_EM  = OFF_GYY + 256 * 3;   // planar [b][c][HW], Bn*CHN*HW
constexpr int OFF_S   = OFF_EM + Bn * CHN * HW;  // Bn*HW
// total = 67072 + 4194304 + 131072 = 4392448 floats (~17.6 MB)
// PX/PY overlay em region (consumed by gram_kernel before em_s writes em).
constexpr int OFF_PX  = OFF_EM;
constexpr int OFF_PY  = OFF_EM + 32 * 256;
}

// ---------------------------------------------------------------------------
// P1: PX[o][t], PY[o][t] sinusoid projections.
// ---------------------------------------------------------------------------
__global__ __launch_bounds__(256) void pxy_kernel(
    const float* __restrict__ w_pos,
    float* __restrict__ PX, float* __restrict__ PY)
{
  const int t = threadIdx.x;
  const int o = blockIdx.x;
  float s[16], c[16];
#pragma unroll
  for (int i = 0; i < 16; i++) {
    float d = expf((float)(2 * i) * (-0.2878231366242557f)); // -ln(1e4)/32
    float a = (float)t * d;
    s[i] = sinf(a);
    c[i] = cosf(a);
  }
  const float* wr = w_pos + o * 64;
  float ax = 0.f, ay = 0.f;
#pragma unroll
  for (int i = 0; i < 16; i++) {
    ax += wr[2 * i] * s[i] + wr[2 * i + 1] * c[i];
    ay += wr[32 + 2 * i] * s[i] + wr[33 + 2 * i] * c[i];
  }
  PX[o * 256 + t] = ax;
  PY[o * 256 + t] = ay;
}

// ---------------------------------------------------------------------------
// P2: M[a][t] = dot_o(PX[:,a], PY[:,t]); GXX/GYY edge Gram terms.
// ---------------------------------------------------------------------------
__global__ __launch_bounds__(256) void gram_kernel(
    const float* __restrict__ PX, const float* __restrict__ PY,
    float* __restrict__ M, float* __restrict__ GXX, float* __restrict__ GYY)
{
  const int t = threadIdx.x;
  const int a = blockIdx.x;

  __shared__ float pxa[32], pxm[32], pxp[32], pya[32], pym[32], pyp[32];
  if (t < 32) {
    pxa[t] = PX[t * 256 + a];
    pya[t] = PY[t * 256 + a];
    pxm[t] = (a >= 2)  ? PX[t * 256 + a - 2] : 0.f;
    pxp[t] = (a < 254) ? PX[t * 256 + a + 2] : 0.f;
    pym[t] = (a >= 2)  ? PY[t * 256 + a - 2] : 0.f;
    pyp[t] = (a < 254) ? PY[t * 256 + a + 2] : 0.f;
  }
  __syncthreads();

  float m = 0.f;
#pragma unroll
  for (int o = 0; o < 32; o++) m += pxa[o] * PY[o * 256 + t];
  M[a * 256 + t] = m;

  if (t < 3) {
    const float* sel = (t == 0) ? pxm : (t == 1) ? pxa : pxp;
    float g = 0.f;
#pragma unroll
    for (int o = 0; o < 32; o++) g += pxa[o] * sel[o];
    GXX[a * 3 + t] = g;
  } else if (t < 6) {
    const int j = t - 3;
    const float* sel = (j == 0) ? pym : (j == 1) ? pya : pyp;
    float g = 0.f;
#pragma unroll
    for (int o = 0; o < 32; o++) g += pya[o] * sel[o];
    GYY[a * 3 + j] = g;
  }
}

// ---------------------------------------------------------------------------
// Kernel 1: em planar [b][c][HW] + smap. All loads/stores lane-contiguous.
// ---------------------------------------------------------------------------
__device__ __forceinline__ void resize_taps(int p, int n, float w[4], int idx[4])
{
#pragma unroll
  for (int r = 0; r < 4; r++) {
    int q = 2 * p - 1 + r;
    idx[r] = min(max(q, 0), 2 * n - 1);
  }
  if (p == 0)          { w[0] = 0.f;        w[1] = 3.f / 7.f; w[2] = 3.f / 7.f; w[3] = 1.f / 7.f; }
  else if (p == n - 1) { w[0] = 1.f / 7.f;  w[1] = 3.f / 7.f; w[2] = 3.f / 7.f; w[3] = 0.f; }
  else                 { w[0] = 0.125f;     w[1] = 0.375f;    w[2] = 0.375f;    w[3] = 0.125f; }
}

__global__ __launch_bounds__(256) void em_s_kernel(
    const float* __restrict__ inp, const float* __restrict__ img,
    const float* __restrict__ w_img, const float* __restrict__ w_comp,
    float* __restrict__ em, float* __restrict__ smap)
{
  const int x = blockIdx.x * 64 + threadIdx.x;
  const int y = blockIdx.y * 4 + threadIdx.y;
  const int b = blockIdx.z;
  const int pix = y * W + x;

  float wy[4], wx[4];
  int ry[4], rx[4];
  resize_taps(y, H, wy, ry);
  resize_taps(x, W, wx, rx);

  float rimg[3];
#pragma unroll
  for (int c = 0; c < 3; c++) {
    const float* ip = img + ((b * 3 + c) * IH) * IW;
    float acc = 0.f;
#pragma unroll
    for (int r = 0; r < 4; r++) {
      const float* rowp = ip + ry[r] * IW;
      float rs = wx[0] * rowp[rx[0]] + wx[1] * rowp[rx[1]] +
                 wx[2] * rowp[rx[2]] + wx[3] * rowp[rx[3]];
      acc += wy[r] * rs;
    }
    rimg[c] = acc;
  }

  float* eb = em + (size_t)b * CHN * HW + pix;
#pragma unroll
  for (int o = 0; o < CHN; o++) {
    eb[(size_t)o * HW] = w_img[o * 3] * rimg[0] + w_img[o * 3 + 1] * rimg[1]
                       + w_img[o * 3 + 2] * rimg[2];
  }

  const float* inpb = inp + (size_t)b * CF * HW;
  float s = 0.f;
#pragma unroll
  for (int c = 0; c < CF; c++) s += inpb[(size_t)c * HW + pix] * w_comp[c];
  smap[b * HW + pix] = s;
}

// ---------------------------------------------------------------------------
// Kernel 2 (fused): per even pixel-pair (float2):
//   fs[k] = dot32_c(em[c][p], em[c][nb_k])  (planar, coalesced)
//   phi[k] = valid_k * sigmoid(smap[nb_k]) * (fs[k] + Gram tables)
//   out[c][p] = sum_k phi[k] * inp[c][nb_k]
// Neighbor offsets are even, pixel pairs even-aligned -> pair validity
// uniform per k; clamped base addresses stay in-bounds, invalid k masked.
// ---------------------------------------------------------------------------
__global__ __launch_bounds__(256) void main_kernel(
    const float* __restrict__ inp, const float* __restrict__ em,
    const float* __restrict__ smap, const float* __restrict__ M,
    const float* __restrict__ GXX, const float* __restrict__ GYY,
    float* __restrict__ out)
{
  const int px = blockIdx.x * 512 + threadIdx.x * 2;  // even pixel index
  const int b = blockIdx.z;
  const int x = px & (W - 1);
  const int y = px >> 8;

  int nb[9];
  bool valid[9];
#pragma unroll
  for (int k = 0; k < 9; k++) {
    const int ky = k / 3, kx = k % 3;
    const int ny = y + 2 * (ky - 1), nx = x + 2 * (kx - 1);
    valid[k] = ((unsigned)ny < (unsigned)H) & ((unsigned)nx < (unsigned)W);
    const int by = min(max(ny, 0), H - 1);
    const int bx = min(max(nx, 0), W - 2);   // even; pair (bx,bx+1) in-bounds
    nb[k] = by * W + bx;
  }

  const float* emb = em + (size_t)b * CHN * HW;
  float2 fs[9];
#pragma unroll
  for (int k = 0; k < 9; k++) fs[k] = make_float2(0.f, 0.f);

#pragma unroll 4
  for (int c = 0; c < CHN; c++) {
    const float* ec = emb + (size_t)c * HW;
    const float2 ctr = *(const float2*)(ec + px);
#pragma unroll
    for (int k = 0; k < 9; k++) {
      const float2 nv = *(const float2*)(ec + nb[k]);
      fs[k].x += ctr.x * nv.x;
      fs[k].y += ctr.y * nv.y;
    }
  }

  const float* sb = smap + (size_t)b * HW;
  float2 phi[9];
#pragma unroll
  for (int k = 0; k < 9; k++) {
    const int ky = k / 3, kx = k % 3;
    const int by = nb[k] >> 8, bx = nb[k] & (W - 1);
    const float gy = GYY[y * 3 + ky];
    const float f0 = fs[k].x + GXX[x * 3 + kx] + gy
                   + M[bx * 256 + y] + M[x * 256 + by];
    const float f1 = fs[k].y + GXX[(x + 1) * 3 + kx] + gy
                   + M[(bx + 1) * 256 + y] + M[(x + 1) * 256 + by];
    const float2 sv = *(const float2*)(sb + nb[k]);
    const float c0 = 1.f / (1.f + expf(-sv.x));
    const float c1 = 1.f / (1.f + expf(-sv.y));
    phi[k].x = valid[k] ? c0 * f0 : 0.f;
    phi[k].y = valid[k] ? c1 * f1 : 0.f;
  }

  const float* inpb = inp + (size_t)b * CF * HW;
  float* outb = out + (size_t)b * CF * HW + px;
#pragma unroll 2
  for (int c = 0; c < CF; c++) {
    const float* ic = inpb + (size_t)c * HW;
    float2 v = *(const float2*)(ic + nb[0]);
    float ax = phi[0].x * v.x, ay = phi[0].y * v.y;
#pragma unroll
    for (int k = 1; k < 9; k++) {
      v = *(const float2*)(ic + nb[k]);
      ax += phi[k].x * v.x;
      ay += phi[k].y * v.y;
    }
    *(float2*)(outb + (size_t)c * HW) = make_float2(ax, ay);
  }
}

// ---------------------------------------------------------------------------
extern "C" void kernel_launch(void* const* d_in, const int* in_sizes, int n_in,
                              void* d_out, int out_size, void* d_ws, size_t ws_size,
                              hipStream_t stream)
{
  const float* inp    = (const float*)d_in[0];
  const float* img    = (const float*)d_in[1];
  const float* w_pos  = (const float*)d_in[2];
  const float* w_img  = (const float*)d_in[3];
  const float* w_comp = (const float*)d_in[4];
  float* out = (float*)d_out;
  float* ws  = (float*)d_ws;

  float* M    = ws + OFF_M;
  float* GXX  = ws + OFF_GXX;
  float* GYY  = ws + OFF_GYY;
  float* em   = ws + OFF_EM;
  float* smap = ws + OFF_S;
  float* PX   = ws + OFF_PX;   // overlays em region (consumed before em written)
  float* PY   = ws + OFF_PY;

  hipLaunchKernelGGL(pxy_kernel, dim3(32), dim3(256), 0, stream, w_pos, PX, PY);
  hipLaunchKernelGGL(gram_kernel, dim3(256), dim3(256), 0, stream,
                     PX, PY, M, GXX, GYY);

  dim3 blk1(64, 4, 1), g1(W / 64, H / 4, Bn);
  hipLaunchKernelGGL(em_s_kernel, g1, blk1, 0, stream,
                     inp, img, w_img, w_comp, em, smap);

  hipLaunchKernelGGL(main_kernel, dim3(HW / 512, 1, Bn), dim3(256), 0, stream,
                     inp, em, smap, M, GXX, GYY, out);
}

// Round 5
// 140.495 us; speedup vs baseline: 1.3676x; 1.2705x over previous
//
#include <hip/hip_runtime.h>
#include <math.h>

namespace {
constexpr int Bn = 2, CF = 64, CHN = 32;
constexpr int H = 256, W = 256, HW = H * W;
constexpr int IH = 512, IW = 512;

// ws layout in floats
constexpr int OFF_MT   = 0;                        // Mt[t][a], 256*256
constexpr int OFF_GXX  = OFF_MT + 256 * 256;       // [3][256] j-major
constexpr int OFF_GYY  = OFF_GXX + 3 * 256;        // [3][256]
constexpr int OFF_EM   = OFF_GYY + 3 * 256;        // planar [b][c][HW]
constexpr int OFF_S    = OFF_EM + Bn * CHN * HW;   // Bn*HW
constexpr int OFF_PHI  = OFF_S + Bn * HW;          // [b][k][HW], Bn*9*HW
constexpr int OFF_RIMG = OFF_PHI + Bn * 9 * HW;    // [b][c3][HW], Bn*3*HW
// total = 65536+768+768+4194304+131072+1179648+393216 = 5965312 floats (~23.9MB)
// PX/PY overlay em region (consumed by gram_kernel before em written).
constexpr int OFF_PX   = OFF_EM;
constexpr int OFF_PY   = OFF_EM + 32 * 256;
}

// ---------------------------------------------------------------------------
// P1: PX[o][t], PY[o][t] sinusoid projections.
// ---------------------------------------------------------------------------
__global__ __launch_bounds__(256) void pxy_kernel(
    const float* __restrict__ w_pos,
    float* __restrict__ PX, float* __restrict__ PY)
{
  const int t = threadIdx.x;
  const int o = blockIdx.x;
  float s[16], c[16];
#pragma unroll
  for (int i = 0; i < 16; i++) {
    float d = expf((float)(2 * i) * (-0.2878231366242557f)); // -ln(1e4)/32
    float a = (float)t * d;
    s[i] = sinf(a);
    c[i] = cosf(a);
  }
  const float* wr = w_pos + o * 64;
  float ax = 0.f, ay = 0.f;
#pragma unroll
  for (int i = 0; i < 16; i++) {
    ax += wr[2 * i] * s[i] + wr[2 * i + 1] * c[i];
    ay += wr[32 + 2 * i] * s[i] + wr[33 + 2 * i] * c[i];
  }
  PX[o * 256 + t] = ax;
  PY[o * 256 + t] = ay;
}

// ---------------------------------------------------------------------------
// P2: Mt[t][a] = dot_o(PX[:,a], PY[:,t])  (transposed so phi reads coalesce).
// Block = t, thread = a: all loads/stores lane-coalesced.
// Block 0 additionally computes GXX/GYY in j-major layout.
// ---------------------------------------------------------------------------
__global__ __launch_bounds__(256) void gram_kernel(
    const float* __restrict__ PX, const float* __restrict__ PY,
    float* __restrict__ Mt, float* __restrict__ GXX, float* __restrict__ GYY)
{
  const int a = threadIdx.x;
  const int t = blockIdx.x;

  float m = 0.f;
#pragma unroll
  for (int o = 0; o < 32; o++) m += PX[o * 256 + a] * PY[o * 256 + t];
  Mt[t * 256 + a] = m;

  if (t == 0) {
#pragma unroll
    for (int j = 0; j < 3; j++) {
      const int nb = a + 2 * (j - 1);
      float gx = 0.f, gy = 0.f;
      if (nb >= 0 && nb < 256) {
#pragma unroll
        for (int o = 0; o < 32; o++) {
          gx += PX[o * 256 + a] * PX[o * 256 + nb];
          gy += PY[o * 256 + a] * PY[o * 256 + nb];
        }
      }
      GXX[j * 256 + a] = gx;
      GYY[j * 256 + a] = gy;
    }
  }
}

// ---------------------------------------------------------------------------
// rimg: antialiased 2x bilinear downsample of img -> [b][c][HW].
// Thread = (b, c, pixel).
// ---------------------------------------------------------------------------
__device__ __forceinline__ void resize_taps(int p, int n, float w[4], int idx[4])
{
#pragma unroll
  for (int r = 0; r < 4; r++) {
    int q = 2 * p - 1 + r;
    idx[r] = min(max(q, 0), 2 * n - 1);
  }
  if (p == 0)          { w[0] = 0.f;        w[1] = 3.f / 7.f; w[2] = 3.f / 7.f; w[3] = 1.f / 7.f; }
  else if (p == n - 1) { w[0] = 1.f / 7.f;  w[1] = 3.f / 7.f; w[2] = 3.f / 7.f; w[3] = 0.f; }
  else                 { w[0] = 0.125f;     w[1] = 0.375f;    w[2] = 0.375f;    w[3] = 0.125f; }
}

__global__ __launch_bounds__(256) void rimg_kernel(
    const float* __restrict__ img, float* __restrict__ rimg)
{
  const int p = blockIdx.x * 256 + threadIdx.x;
  const int c = blockIdx.y;
  const int b = blockIdx.z;
  const int x = p & (W - 1);
  const int y = p >> 8;

  float wy[4], wx[4];
  int ry[4], rx[4];
  resize_taps(y, H, wy, ry);
  resize_taps(x, W, wx, rx);

  const float* ip = img + ((size_t)(b * 3 + c) * IH) * IW;
  float acc = 0.f;
#pragma unroll
  for (int r = 0; r < 4; r++) {
    const float* rowp = ip + ry[r] * IW;
    float rs = wx[0] * rowp[rx[0]] + wx[1] * rowp[rx[1]] +
               wx[2] * rowp[rx[2]] + wx[3] * rowp[rx[3]];
    acc += wy[r] * rs;
  }
  rimg[((size_t)(b * 3 + c)) * HW + p] = acc;
}

// ---------------------------------------------------------------------------
// em_proj: em[b][o][p] = dot3(w_img[o], rimg[b][:,p]).
// Thread = (b, o-quad, pixel).
// ---------------------------------------------------------------------------
__global__ __launch_bounds__(256) void em_proj_kernel(
    const float* __restrict__ rimg, const float* __restrict__ w_img,
    float* __restrict__ em)
{
  const int p = blockIdx.x * 256 + threadIdx.x;
  const int oq = blockIdx.y;   // 0..7, channels 4*oq..4*oq+3
  const int b = blockIdx.z;
  const float r0 = rimg[((size_t)(b * 3 + 0)) * HW + p];
  const float r1 = rimg[((size_t)(b * 3 + 1)) * HW + p];
  const float r2 = rimg[((size_t)(b * 3 + 2)) * HW + p];
  float* eb = em + (size_t)b * CHN * HW;
#pragma unroll
  for (int i = 0; i < 4; i++) {
    const int o = oq * 4 + i;
    eb[(size_t)o * HW + p] =
        w_img[o * 3] * r0 + w_img[o * 3 + 1] * r1 + w_img[o * 3 + 2] * r2;
  }
}

// ---------------------------------------------------------------------------
// smap[b][p] = dot_c(inp[b,:,p], w_comp). Block = 64 pixels x 4 ch-groups of
// 16; LDS reduction. 8192 waves total.
// ---------------------------------------------------------------------------
__global__ __launch_bounds__(256) void smap_kernel(
    const float* __restrict__ inp, const float* __restrict__ w_comp,
    float* __restrict__ smap)
{
  __shared__ float red[256];
  const int lane = threadIdx.x & 63;
  const int cg = threadIdx.x >> 6;         // 0..3
  const int p = blockIdx.x * 64 + lane;
  const int b = blockIdx.z;

  const float* ib = inp + (size_t)b * CF * HW + (size_t)cg * 16 * HW + p;
  float a0 = 0.f, a1 = 0.f, a2 = 0.f, a3 = 0.f;
#pragma unroll
  for (int c = 0; c < 16; c += 4) {
    a0 += ib[(size_t)(c + 0) * HW] * w_comp[cg * 16 + c + 0];
    a1 += ib[(size_t)(c + 1) * HW] * w_comp[cg * 16 + c + 1];
    a2 += ib[(size_t)(c + 2) * HW] * w_comp[cg * 16 + c + 2];
    a3 += ib[(size_t)(c + 3) * HW] * w_comp[cg * 16 + c + 3];
  }
  red[threadIdx.x] = (a0 + a1) + (a2 + a3);
  __syncthreads();
  if (threadIdx.x < 64) {
    smap[(size_t)b * HW + blockIdx.x * 64 + threadIdx.x] =
        red[threadIdx.x] + red[threadIdx.x + 64] +
        red[threadIdx.x + 128] + red[threadIdx.x + 192];
  }
}

// ---------------------------------------------------------------------------
// phi[b][k][p] = valid_k * sigmoid(smap[nb]) *
//   ( dot32_c(em[c][p], em[c][nb]) + GXX[kx][x] + GYY[ky][y]
//     + Mt[y][cnx] + Mt[cny][x] )
// Thread = (b, k, pixel). All accesses lane-coalesced (y uniform per wave).
// ---------------------------------------------------------------------------
__global__ __launch_bounds__(256) void phi_kernel(
    const float* __restrict__ em, const float* __restrict__ smap,
    const float* __restrict__ Mt, const float* __restrict__ GXX,
    const float* __restrict__ GYY, float* __restrict__ phi)
{
  const int p = blockIdx.x * 256 + threadIdx.x;
  const int k = blockIdx.y;
  const int b = blockIdx.z;
  const int x = p & (W - 1);
  const int y = p >> 8;
  const int ky = k / 3, kx = k % 3;
  const int ny = y + 2 * (ky - 1), nx = x + 2 * (kx - 1);
  const bool valid = ((unsigned)ny < (unsigned)H) & ((unsigned)nx < (unsigned)W);
  const int cy = min(max(ny, 0), H - 1);
  const int cx = min(max(nx, 0), W - 1);
  const int np = cy * W + cx;

  const float* eb = em + (size_t)b * CHN * HW;
  float a0 = 0.f, a1 = 0.f, a2 = 0.f, a3 = 0.f;
#pragma unroll
  for (int c = 0; c < CHN; c += 4) {
    a0 += eb[(size_t)(c + 0) * HW + p] * eb[(size_t)(c + 0) * HW + np];
    a1 += eb[(size_t)(c + 1) * HW + p] * eb[(size_t)(c + 1) * HW + np];
    a2 += eb[(size_t)(c + 2) * HW + p] * eb[(size_t)(c + 2) * HW + np];
    a3 += eb[(size_t)(c + 3) * HW + p] * eb[(size_t)(c + 3) * HW + np];
  }
  float fs = (a0 + a1) + (a2 + a3);
  fs += GXX[kx * 256 + x] + GYY[ky * 256 + y] + Mt[y * 256 + cx] + Mt[cy * 256 + x];

  const float s = smap[(size_t)b * HW + np];
  const float cs = 1.f / (1.f + expf(-s));
  phi[((size_t)(b * 9 + k)) * HW + p] = valid ? cs * fs : 0.f;
}

// ---------------------------------------------------------------------------
// gather: out[b][c][p] = sum_k phi[b][k][p] * inp[b][c][nb_k].
// Thread = (cg of 4 channels, pixel, b); cg fastest in grid so row reuse for
// a channel slice stays on one XCD.
// ---------------------------------------------------------------------------
__global__ __launch_bounds__(256) void gather_kernel(
    const float* __restrict__ inp, const float* __restrict__ phi,
    float* __restrict__ out)
{
  const int cg = blockIdx.x;               // 0..15
  const int p = blockIdx.y * 256 + threadIdx.x;
  const int b = blockIdx.z;
  const int x = p & (W - 1);
  const int y = p >> 8;

  float ph[9];
  int nb[9];
#pragma unroll
  for (int k = 0; k < 9; k++) {
    const int ky = k / 3, kx = k % 3;
    const int ny = y + 2 * (ky - 1), nx = x + 2 * (kx - 1);
    const int cy = min(max(ny, 0), H - 1);
    const int cx = min(max(nx, 0), W - 1);
    nb[k] = cy * W + cx;
    ph[k] = phi[((size_t)(b * 9 + k)) * HW + p];  // 0 when invalid
  }

  const float* ib = inp + (size_t)b * CF * HW + (size_t)cg * 4 * HW;
  float* ob = out + (size_t)b * CF * HW + (size_t)cg * 4 * HW;
#pragma unroll
  for (int c = 0; c < 4; c++) {
    const float* ic = ib + (size_t)c * HW;
    float acc = ph[0] * ic[nb[0]];
#pragma unroll
    for (int k = 1; k < 9; k++) acc += ph[k] * ic[nb[k]];
    ob[(size_t)c * HW + p] = acc;
  }
}

// ---------------------------------------------------------------------------
extern "C" void kernel_launch(void* const* d_in, const int* in_sizes, int n_in,
                              void* d_out, int out_size, void* d_ws, size_t ws_size,
                              hipStream_t stream)
{
  const float* inp    = (const float*)d_in[0];
  const float* img    = (const float*)d_in[1];
  const float* w_pos  = (const float*)d_in[2];
  const float* w_img  = (const float*)d_in[3];
  const float* w_comp = (const float*)d_in[4];
  float* out = (float*)d_out;
  float* ws  = (float*)d_ws;

  float* Mt   = ws + OFF_MT;
  float* GXX  = ws + OFF_GXX;
  float* GYY  = ws + OFF_GYY;
  float* em   = ws + OFF_EM;
  float* smap = ws + OFF_S;
  float* phi  = ws + OFF_PHI;
  float* rimg = ws + OFF_RIMG;
  float* PX   = ws + OFF_PX;   // overlays em (consumed before em written)
  float* PY   = ws + OFF_PY;

  hipLaunchKernelGGL(pxy_kernel, dim3(32), dim3(256), 0, stream, w_pos, PX, PY);
  hipLaunchKernelGGL(gram_kernel, dim3(256), dim3(256), 0, stream,
                     PX, PY, Mt, GXX, GYY);

  hipLaunchKernelGGL(rimg_kernel, dim3(HW / 256, 3, Bn), dim3(256), 0, stream,
                     img, rimg);
  hipLaunchKernelGGL(em_proj_kernel, dim3(HW / 256, 8, Bn), dim3(256), 0, stream,
                     rimg, w_img, em);
  hipLaunchKernelGGL(smap_kernel, dim3(HW / 64, 1, Bn), dim3(256), 0, stream,
                     inp, w_comp, smap);

  hipLaunchKernelGGL(phi_kernel, dim3(HW / 256, 9, Bn), dim3(256), 0, stream,
                     em, smap, Mt, GXX, GYY, phi);

  hipLaunchKernelGGL(gather_kernel, dim3(CF / 4, HW / 256, Bn), dim3(256), 0, stream,
                     inp, phi, out);
}

// Round 6
// 125.124 us; speedup vs baseline: 1.5356x; 1.1228x over previous
//
#include <hip/hip_runtime.h>
#include <math.h>

namespace {
constexpr int Bn = 2, CF = 64;
constexpr int H = 256, W = 256, HW = H * W;
constexpr int IH = 512, IW = 512;

// ws layout in floats
constexpr int OFF_MT   = 0;                        // Mt[t][a], 256*256
constexpr int OFF_GXX  = OFF_MT + 256 * 256;       // [3][256] j-major
constexpr int OFF_GYY  = OFF_GXX + 3 * 256;        // [3][256]
constexpr int OFF_G    = OFF_GYY + 3 * 256;        // 3x3 = w_img^T w_img (pad 16)
constexpr int OFF_RIMG = OFF_G + 16;               // [b][c3][HW], Bn*3*HW
constexpr int OFF_S    = OFF_RIMG + Bn * 3 * HW;   // Bn*HW
constexpr int OFF_PHI  = OFF_S + Bn * HW;          // [b][k][HW], Bn*9*HW
// total = 65536+768+768+16+393216+131072+1179648 = 1771024 floats (~7.1 MB)
// PX/PY (32*256 each) overlay the RIMG region: consumed by gram_kernel
// before rimg_kernel writes it (same stream => ordered).
constexpr int OFF_PX   = OFF_RIMG;
constexpr int OFF_PY   = OFF_RIMG + 32 * 256;
}

// ---------------------------------------------------------------------------
// P1: PX[o][t], PY[o][t] sinusoid projections.
// ---------------------------------------------------------------------------
__global__ __launch_bounds__(256) void pxy_kernel(
    const float* __restrict__ w_pos,
    float* __restrict__ PX, float* __restrict__ PY)
{
  const int t = threadIdx.x;
  const int o = blockIdx.x;
  float s[16], c[16];
#pragma unroll
  for (int i = 0; i < 16; i++) {
    float d = expf((float)(2 * i) * (-0.2878231366242557f)); // -ln(1e4)/32
    float a = (float)t * d;
    s[i] = sinf(a);
    c[i] = cosf(a);
  }
  const float* wr = w_pos + o * 64;
  float ax = 0.f, ay = 0.f;
#pragma unroll
  for (int i = 0; i < 16; i++) {
    ax += wr[2 * i] * s[i] + wr[2 * i + 1] * c[i];
    ay += wr[32 + 2 * i] * s[i] + wr[33 + 2 * i] * c[i];
  }
  PX[o * 256 + t] = ax;
  PY[o * 256 + t] = ay;
}

// ---------------------------------------------------------------------------
// P2: Mt[t][a] = dot_o(PX[:,a], PY[:,t]) (transposed: phi reads coalesce).
// Block 0 also computes GXX/GYY (j-major) and G = w_img^T w_img (3x3).
// ---------------------------------------------------------------------------
__global__ __launch_bounds__(256) void gram_kernel(
    const float* __restrict__ PX, const float* __restrict__ PY,
    const float* __restrict__ w_img,
    float* __restrict__ Mt, float* __restrict__ GXX, float* __restrict__ GYY,
    float* __restrict__ G)
{
  const int a = threadIdx.x;
  const int t = blockIdx.x;

  float m = 0.f;
#pragma unroll
  for (int o = 0; o < 32; o++) m += PX[o * 256 + a] * PY[o * 256 + t];
  Mt[t * 256 + a] = m;

  if (t == 0) {
#pragma unroll
    for (int j = 0; j < 3; j++) {
      const int nb = a + 2 * (j - 1);
      float gx = 0.f, gy = 0.f;
      if (nb >= 0 && nb < 256) {
#pragma unroll
        for (int o = 0; o < 32; o++) {
          gx += PX[o * 256 + a] * PX[o * 256 + nb];
          gy += PY[o * 256 + a] * PY[o * 256 + nb];
        }
      }
      GXX[j * 256 + a] = gx;
      GYY[j * 256 + a] = gy;
    }
    if (a < 9) {
      const int i = a / 3, j = a % 3;
      float g = 0.f;
#pragma unroll
      for (int o = 0; o < 32; o++) g += w_img[o * 3 + i] * w_img[o * 3 + j];
      G[a] = g;
    }
  }
}

// ---------------------------------------------------------------------------
// rimg: antialiased 2x bilinear downsample of img -> [b][c][HW].
// ---------------------------------------------------------------------------
__device__ __forceinline__ void resize_taps(int p, int n, float w[4], int idx[4])
{
#pragma unroll
  for (int r = 0; r < 4; r++) {
    int q = 2 * p - 1 + r;
    idx[r] = min(max(q, 0), 2 * n - 1);
  }
  if (p == 0)          { w[0] = 0.f;        w[1] = 3.f / 7.f; w[2] = 3.f / 7.f; w[3] = 1.f / 7.f; }
  else if (p == n - 1) { w[0] = 1.f / 7.f;  w[1] = 3.f / 7.f; w[2] = 3.f / 7.f; w[3] = 0.f; }
  else                 { w[0] = 0.125f;     w[1] = 0.375f;    w[2] = 0.375f;    w[3] = 0.125f; }
}

__global__ __launch_bounds__(256) void rimg_kernel(
    const float* __restrict__ img, float* __restrict__ rimg)
{
  const int p = blockIdx.x * 256 + threadIdx.x;
  const int c = blockIdx.y;
  const int b = blockIdx.z;
  const int x = p & (W - 1);
  const int y = p >> 8;

  float wy[4], wx[4];
  int ry[4], rx[4];
  resize_taps(y, H, wy, ry);
  resize_taps(x, W, wx, rx);

  const float* ip = img + ((size_t)(b * 3 + c) * IH) * IW;
  float acc = 0.f;
#pragma unroll
  for (int r = 0; r < 4; r++) {
    const float* rowp = ip + ry[r] * IW;
    float rs = wx[0] * rowp[rx[0]] + wx[1] * rowp[rx[1]] +
               wx[2] * rowp[rx[2]] + wx[3] * rowp[rx[3]];
    acc += wy[r] * rs;
  }
  rimg[((size_t)(b * 3 + c)) * HW + p] = acc;
}

// ---------------------------------------------------------------------------
// smap[b][p] = dot_c(inp[b,:,p], w_comp). 64 pix x 4 ch-groups, LDS reduce.
// ---------------------------------------------------------------------------
__global__ __launch_bounds__(256) void smap_kernel(
    const float* __restrict__ inp, const float* __restrict__ w_comp,
    float* __restrict__ smap)
{
  __shared__ float red[256];
  const int lane = threadIdx.x & 63;
  const int cg = threadIdx.x >> 6;         // 0..3
  const int p = blockIdx.x * 64 + lane;
  const int b = blockIdx.z;

  const float* ib = inp + (size_t)b * CF * HW + (size_t)cg * 16 * HW + p;
  float a0 = 0.f, a1 = 0.f, a2 = 0.f, a3 = 0.f;
#pragma unroll
  for (int c = 0; c < 16; c += 4) {
    a0 += ib[(size_t)(c + 0) * HW] * w_comp[cg * 16 + c + 0];
    a1 += ib[(size_t)(c + 1) * HW] * w_comp[cg * 16 + c + 1];
    a2 += ib[(size_t)(c + 2) * HW] * w_comp[cg * 16 + c + 2];
    a3 += ib[(size_t)(c + 3) * HW] * w_comp[cg * 16 + c + 3];
  }
  red[threadIdx.x] = (a0 + a1) + (a2 + a3);
  __syncthreads();
  if (threadIdx.x < 64) {
    smap[(size_t)b * HW + blockIdx.x * 64 + threadIdx.x] =
        red[threadIdx.x] + red[threadIdx.x + 64] +
        red[threadIdx.x + 128] + red[threadIdx.x + 192];
  }
}

// ---------------------------------------------------------------------------
// phi[b][k][p] = valid_k * sigmoid(smap[nb]) *
//   ( rimg[p]^T G rimg[nb] + GXX[kx][x] + GYY[ky][y] + Mt[y][cx] + Mt[cy][x] )
// The 32-channel em dot collapses to a 3x3 quadratic form (em = W rimg).
// ---------------------------------------------------------------------------
__global__ __launch_bounds__(256) void phi_kernel(
    const float* __restrict__ rimg, const float* __restrict__ smap,
    const float* __restrict__ Mt, const float* __restrict__ GXX,
    const float* __restrict__ GYY, const float* __restrict__ G,
    float* __restrict__ phi)
{
  const int p = blockIdx.x * 256 + threadIdx.x;
  const int k = blockIdx.y;
  const int b = blockIdx.z;
  const int x = p & (W - 1);
  const int y = p >> 8;
  const int ky = k / 3, kx = k % 3;
  const int ny = y + 2 * (ky - 1), nx = x + 2 * (kx - 1);
  const bool valid = ((unsigned)ny < (unsigned)H) & ((unsigned)nx < (unsigned)W);
  const int cy = min(max(ny, 0), H - 1);
  const int cx = min(max(nx, 0), W - 1);
  const int np = cy * W + cx;

  const float* rb = rimg + (size_t)b * 3 * HW;
  const float r0 = rb[p],            r1 = rb[HW + p],      r2 = rb[2 * HW + p];
  const float n0 = rb[np],           n1 = rb[HW + np],     n2 = rb[2 * HW + np];

  const float g0 = G[0], g1 = G[1], g2 = G[2];
  const float g3 = G[3], g4 = G[4], g5 = G[5];
  const float g6 = G[6], g7 = G[7], g8 = G[8];

  float fs = r0 * (g0 * n0 + g1 * n1 + g2 * n2)
           + r1 * (g3 * n0 + g4 * n1 + g5 * n2)
           + r2 * (g6 * n0 + g7 * n1 + g8 * n2);
  fs += GXX[kx * 256 + x] + GYY[ky * 256 + y] + Mt[y * 256 + cx] + Mt[cy * 256 + x];

  const float s = smap[(size_t)b * HW + np];
  const float cs = 1.f / (1.f + expf(-s));
  phi[((size_t)(b * 9 + k)) * HW + p] = valid ? cs * fs : 0.f;
}

// ---------------------------------------------------------------------------
// gather: out[b][c][p] = sum_k phi[b][k][p] * inp[b][c][nb_k].
// Thread = (cg of 4 channels, pixel, b).
// ---------------------------------------------------------------------------
__global__ __launch_bounds__(256) void gather_kernel(
    const float* __restrict__ inp, const float* __restrict__ phi,
    float* __restrict__ out)
{
  const int cg = blockIdx.x;               // 0..15
  const int p = blockIdx.y * 256 + threadIdx.x;
  const int b = blockIdx.z;
  const int x = p & (W - 1);
  const int y = p >> 8;

  float ph[9];
  int nb[9];
#pragma unroll
  for (int k = 0; k < 9; k++) {
    const int ky = k / 3, kx = k % 3;
    const int ny = y + 2 * (ky - 1), nx = x + 2 * (kx - 1);
    const int cy = min(max(ny, 0), H - 1);
    const int cx = min(max(nx, 0), W - 1);
    nb[k] = cy * W + cx;
    ph[k] = phi[((size_t)(b * 9 + k)) * HW + p];  // 0 when invalid
  }

  const float* ib = inp + (size_t)b * CF * HW + (size_t)cg * 4 * HW;
  float* ob = out + (size_t)b * CF * HW + (size_t)cg * 4 * HW;
#pragma unroll
  for (int c = 0; c < 4; c++) {
    const float* ic = ib + (size_t)c * HW;
    float acc = ph[0] * ic[nb[0]];
#pragma unroll
    for (int k = 1; k < 9; k++) acc += ph[k] * ic[nb[k]];
    ob[(size_t)c * HW + p] = acc;
  }
}

// ---------------------------------------------------------------------------
extern "C" void kernel_launch(void* const* d_in, const int* in_sizes, int n_in,
                              void* d_out, int out_size, void* d_ws, size_t ws_size,
                              hipStream_t stream)
{
  const float* inp    = (const float*)d_in[0];
  const float* img    = (const float*)d_in[1];
  const float* w_pos  = (const float*)d_in[2];
  const float* w_img  = (const float*)d_in[3];
  const float* w_comp = (const float*)d_in[4];
  float* out = (float*)d_out;
  float* ws  = (float*)d_ws;

  float* Mt   = ws + OFF_MT;
  float* GXX  = ws + OFF_GXX;
  float* GYY  = ws + OFF_GYY;
  float* G    = ws + OFF_G;
  float* rimg = ws + OFF_RIMG;
  float* smap = ws + OFF_S;
  float* phi  = ws + OFF_PHI;
  float* PX   = ws + OFF_PX;   // overlays rimg (consumed before rimg written)
  float* PY   = ws + OFF_PY;

  hipLaunchKernelGGL(pxy_kernel, dim3(32), dim3(256), 0, stream, w_pos, PX, PY);
  hipLaunchKernelGGL(gram_kernel, dim3(256), dim3(256), 0, stream,
                     PX, PY, w_img, Mt, GXX, GYY, G);

  hipLaunchKernelGGL(rimg_kernel, dim3(HW / 256, 3, Bn), dim3(256), 0, stream,
                     img, rimg);
  hipLaunchKernelGGL(smap_kernel, dim3(HW / 64, 1, Bn), dim3(256), 0, stream,
                     inp, w_comp, smap);

  hipLaunchKernelGGL(phi_kernel, dim3(HW / 256, 9, Bn), dim3(256), 0, stream,
                     rimg, smap, Mt, GXX, GYY, G, phi);

  hipLaunchKernelGGL(gather_kernel, dim3(CF / 4, HW / 256, Bn), dim3(256), 0, stream,
                     inp, phi, out);
}